// Round 1
// baseline (709.506 us; speedup 1.0000x reference)
//
#include <hip/hip_runtime.h>
#include <hip/hip_bf16.h>
#include <cstdint>

#define B_ROWS   1024
#define N_DB     100000
#define N_PAD    100096      // 782 * 128
#define DIM      1024
#define TOPK     70
#define CAND_MAX 1024
#define T_CAND   0.085f

typedef __bf16 bf16x8 __attribute__((ext_vector_type(8)));
typedef float  f32x4  __attribute__((ext_vector_type(4)));

__device__ __forceinline__ unsigned short f32_to_bf16(float f) {
    uint32_t u = __float_as_uint(f);
    uint32_t r = (u + 0x7fffu + ((u >> 16) & 1u)) >> 16;
    return (unsigned short)r;
}

__device__ __forceinline__ void gload_lds16(const void* g, void* l) {
    __builtin_amdgcn_global_load_lds(
        (const __attribute__((address_space(1))) unsigned int*)g,
        (__attribute__((address_space(3))) unsigned int*)l, 16, 0, 0);
}

// ---------------- Phase 0: row-normalize (f64 norm) + bf16 convert ----------------
__global__ void prep_normalize(const float* __restrict__ src, int n_valid, 
                               unsigned short* __restrict__ dst,
                               double* __restrict__ inv_out) {
    const int row = blockIdx.x;
    const int t = threadIdx.x;
    __shared__ double s_part[4];
    __shared__ double s_inv;
    unsigned short* drow = dst + (size_t)row * DIM;
    if (row < n_valid) {
        const float4* srow = (const float4*)(src + (size_t)row * DIM);
        float4 v = srow[t];
        double acc = (double)v.x * v.x + (double)v.y * v.y +
                     (double)v.z * v.z + (double)v.w * v.w;
        #pragma unroll
        for (int off = 32; off > 0; off >>= 1) acc += __shfl_down(acc, off);
        if ((t & 63) == 0) s_part[t >> 6] = acc;
        __syncthreads();
        if (t == 0) {
            double nn = sqrt(s_part[0] + s_part[1] + s_part[2] + s_part[3]);
            if (nn < 1e-12) nn = 1e-12;
            double iv = 1.0 / nn;
            s_inv = iv;
            inv_out[row] = iv;
        }
        __syncthreads();
        float iv = (float)s_inv;
        ushort4 o;
        o.x = f32_to_bf16(v.x * iv);
        o.y = f32_to_bf16(v.y * iv);
        o.z = f32_to_bf16(v.z * iv);
        o.w = f32_to_bf16(v.w * iv);
        ((ushort4*)drow)[t] = o;
    } else {
        ushort4 z; z.x = z.y = z.z = z.w = 0;
        ((ushort4*)drow)[t] = z;
        if (t == 0) inv_out[row] = 0.0;
    }
}

// ---------------- Phase A: bf16 MFMA GEMM, threshold-append candidates ----------------
__launch_bounds__(256, 2)
__global__ void approx_topk_gemm(const unsigned short* __restrict__ Abf,  // [1024][1024]
                                 const unsigned short* __restrict__ Bbf,  // [N_PAD][1024]
                                 int* __restrict__ cand_cnt,
                                 int* __restrict__ cand_idx) {
    __shared__ unsigned short At[128 * 32];
    __shared__ unsigned short Bt[128 * 32];
    const int t    = threadIdx.x;
    const int lane = t & 63;
    const int w    = t >> 6;
    const int wr   = w >> 1, wc = w & 1;
    const int r16  = lane & 15, kq = lane >> 4;
    const int brow0 = blockIdx.x * 128;   // 8 row tiles (query)
    const int bcol0 = blockIdx.y * 128;   // 782 col tiles (db)

    f32x4 acc[4][4];
    #pragma unroll
    for (int m = 0; m < 4; ++m)
        #pragma unroll
        for (int n = 0; n < 4; ++n)
            acc[m][n] = (f32x4){0.f, 0.f, 0.f, 0.f};

    const int srow = t >> 2;        // 0..63
    const int sseg = t & 3;         // 16B segment within 64B row-chunk

    for (int kt = 0; kt < DIM / 32; ++kt) {
        #pragma unroll
        for (int h = 0; h < 2; ++h) {
            int rr = h * 64 + srow;
            gload_lds16(Abf + (size_t)(brow0 + rr) * DIM + kt * 32 + sseg * 8,
                        &At[rr * 32 + sseg * 8]);
            gload_lds16(Bbf + (size_t)(bcol0 + rr) * DIM + kt * 32 + sseg * 8,
                        &Bt[rr * 32 + sseg * 8]);
        }
        __syncthreads();
        bf16x8 af[4], bfr[4];
        #pragma unroll
        for (int m = 0; m < 4; ++m)
            af[m] = *(const bf16x8*)&At[(wr * 64 + m * 16 + r16) * 32 + kq * 8];
        #pragma unroll
        for (int n = 0; n < 4; ++n)
            bfr[n] = *(const bf16x8*)&Bt[(wc * 64 + n * 16 + r16) * 32 + kq * 8];
        #pragma unroll
        for (int m = 0; m < 4; ++m)
            #pragma unroll
            for (int n = 0; n < 4; ++n)
                acc[m][n] = __builtin_amdgcn_mfma_f32_16x16x32_bf16(af[m], bfr[n], acc[m][n], 0, 0, 0);
        __syncthreads();
    }

    // epilogue: C/D mapping col = lane&15, row = (lane>>4)*4 + reg
    #pragma unroll
    for (int m = 0; m < 4; ++m) {
        #pragma unroll
        for (int n = 0; n < 4; ++n) {
            const int c = bcol0 + wc * 64 + n * 16 + r16;
            #pragma unroll
            for (int reg = 0; reg < 4; ++reg) {
                float v = acc[m][n][reg];
                if (v >= T_CAND && c < N_DB) {
                    int r = brow0 + wr * 64 + m * 16 + kq * 4 + reg;
                    int pos = atomicAdd(&cand_cnt[r], 1);
                    if (pos < CAND_MAX) cand_idx[r * CAND_MAX + pos] = c;
                }
            }
        }
    }
}

// ---------------- Phase B: exact f64 sims for candidates ----------------
__global__ void exact_cand_sims(const float* __restrict__ query,
                                const float* __restrict__ en_db,
                                const double* __restrict__ q_inv,
                                const double* __restrict__ db_inv,
                                const int* __restrict__ cand_cnt,
                                const int* __restrict__ cand_idx,
                                double* __restrict__ cand_sim) {
    const int b = blockIdx.x;
    const int lane = threadIdx.x & 63;
    const int wid = threadIdx.x >> 6;
    const int wglob = blockIdx.y * 4 + wid;       // 0..15 waves per row
    int cnt = cand_cnt[b];
    if (cnt > CAND_MAX) cnt = CAND_MAX;
    const float4* qg = (const float4*)(query + (size_t)b * DIM);
    float4 qr[4];
    #pragma unroll
    for (int j = 0; j < 4; ++j) qr[j] = qg[j * 64 + lane];
    const double qi = q_inv[b];
    for (int c = wglob; c < cnt; c += 16) {
        const int idx = cand_idx[b * CAND_MAX + c];
        const float4* dv = (const float4*)(en_db + (size_t)idx * DIM);
        double acc = 0.0;
        #pragma unroll
        for (int j = 0; j < 4; ++j) {
            float4 x = dv[j * 64 + lane];
            float4 q = qr[j];
            acc += (double)x.x * q.x + (double)x.y * q.y +
                   (double)x.z * q.z + (double)x.w * q.w;
        }
        #pragma unroll
        for (int off = 32; off > 0; off >>= 1) acc += __shfl_down(acc, off);
        if (lane == 0) cand_sim[b * CAND_MAX + c] = acc * qi * db_inv[idx];
    }
}

// ---------------- Phase C: sort, top-70, gumbel softmax, gather-combine ----------------
__launch_bounds__(256)
__global__ void finalize_kernel(const float* __restrict__ noise,
                                const float* __restrict__ es_db,
                                const int* __restrict__ cand_cnt,
                                const int* __restrict__ cand_idx,
                                const double* __restrict__ cand_sim,
                                float* __restrict__ out) {
    __shared__ double s_sim[CAND_MAX];
    __shared__ int    s_idx[CAND_MAX];
    __shared__ double s_logit[TOPK];
    __shared__ float  s_w[TOPK];
    __shared__ int    s_top[TOPK];
    const int b = blockIdx.x;
    const int t = threadIdx.x;
    int cnt = min(cand_cnt[b], CAND_MAX);
    for (int i = t; i < CAND_MAX; i += 256) {
        if (i < cnt) {
            s_sim[i] = cand_sim[b * CAND_MAX + i];
            s_idx[i] = cand_idx[b * CAND_MAX + i];
        } else {
            s_sim[i] = -1e300;
            s_idx[i] = 0x7fffffff;
        }
    }
    __syncthreads();
    // bitonic sort: final order = sim desc, tie -> idx asc (lax.top_k semantics)
    for (int k = 2; k <= CAND_MAX; k <<= 1) {
        for (int j = k >> 1; j > 0; j >>= 1) {
            for (int i = t; i < CAND_MAX; i += 256) {
                int l = i ^ j;
                if (l > i) {
                    double si = s_sim[i], sl = s_sim[l];
                    int ii = s_idx[i], il = s_idx[l];
                    // "after": ranks later in desired order
                    bool iAfter = (si < sl) || (si == sl && ii > il);
                    bool lAfter = (sl < si) || (sl == si && il > ii);
                    bool dosw = (((i & k) == 0) ? iAfter : lAfter);
                    if (dosw) {
                        s_sim[i] = sl; s_sim[l] = si;
                        s_idx[i] = il; s_idx[l] = ii;
                    }
                }
            }
            __syncthreads();
        }
    }
    if (t < TOPK) {
        double sim = s_sim[t];
        double u = (double)noise[b * TOPK + t];
        double g = -log(-log(u + 1e-10) + 1e-10);
        s_logit[t] = (sim + g) / 0.1;
        s_top[t] = s_idx[t];
    }
    __syncthreads();
    if (t == 0) {
        double mx = -1e300;
        for (int k = 0; k < TOPK; ++k) mx = fmax(mx, s_logit[k]);
        double sum = 0.0;
        for (int k = 0; k < TOPK; ++k) {
            double ev = exp(s_logit[k] - mx);
            s_logit[k] = ev;
            sum += ev;
        }
        double isum = 1.0 / sum;
        for (int k = 0; k < TOPK; ++k) s_w[k] = (float)(s_logit[k] * isum);
    }
    __syncthreads();
    float4 accv = {0.f, 0.f, 0.f, 0.f};
    for (int k = 0; k < TOPK; ++k) {
        int idx = s_top[k];
        if (idx < N_DB) {
            float4 v = ((const float4*)(es_db + (size_t)idx * DIM))[t];
            float wk = s_w[k];
            accv.x += wk * v.x;
            accv.y += wk * v.y;
            accv.z += wk * v.z;
            accv.w += wk * v.w;
        }
    }
    ((float4*)(out + (size_t)b * DIM))[t] = accv;
}

extern "C" void kernel_launch(void* const* d_in, const int* in_sizes, int n_in,
                              void* d_out, int out_size, void* d_ws, size_t ws_size,
                              hipStream_t stream) {
    const float* query = (const float*)d_in[0];
    const float* en_db = (const float*)d_in[1];
    const float* es_db = (const float*)d_in[2];
    const float* noise = (const float*)d_in[3];
    float* out = (float*)d_out;

    char* ws = (char*)d_ws;
    size_t off = 0;
    unsigned short* db_bf = (unsigned short*)(ws + off); off += (size_t)N_PAD * DIM * 2;  // 204,996,608
    double* db_inv        = (double*)(ws + off);         off += (size_t)N_PAD * 8;        // 800,768
    unsigned short* q_bf  = (unsigned short*)(ws + off); off += (size_t)B_ROWS * DIM * 2; // 2,097,152
    double* q_inv         = (double*)(ws + off);         off += (size_t)B_ROWS * 8;       // 8,192
    int* cand_cnt         = (int*)(ws + off);            off += (size_t)B_ROWS * 4;       // 4,096
    int* cand_idx         = (int*)(ws + off);            off += (size_t)B_ROWS * CAND_MAX * 4; // 4 MB
    double* cand_sim      = (double*)(ws + off);         off += (size_t)B_ROWS * CAND_MAX * 8; // 8 MB

    hipMemsetAsync(cand_cnt, 0, (size_t)B_ROWS * 4, stream);

    prep_normalize<<<N_PAD, 256, 0, stream>>>(en_db, N_DB, db_bf, db_inv);
    prep_normalize<<<B_ROWS, 256, 0, stream>>>(query, B_ROWS, q_bf, q_inv);

    approx_topk_gemm<<<dim3(8, 782), 256, 0, stream>>>(q_bf, db_bf, cand_cnt, cand_idx);

    exact_cand_sims<<<dim3(B_ROWS, 4), 256, 0, stream>>>(query, en_db, q_inv, db_inv,
                                                         cand_cnt, cand_idx, cand_sim);

    finalize_kernel<<<B_ROWS, 256, 0, stream>>>(noise, es_db, cand_cnt, cand_idx,
                                                cand_sim, out);
}

// Round 2
// 527.694 us; speedup vs baseline: 1.3445x; 1.3445x over previous
//
#include <hip/hip_runtime.h>
#include <hip/hip_bf16.h>
#include <cstdint>

#define B_ROWS   1024
#define N_DB     100000
#define N_PAD    100096      // 782 * 128
#define DIM      1024
#define TOPK     70
#define CAND_MAX 1024
#define SURV_MAX 256
#define T_CAND   0.085f
#define FILT_MARGIN 2.5e-3f

typedef __bf16 bf16x8 __attribute__((ext_vector_type(8)));
typedef float  f32x4  __attribute__((ext_vector_type(4)));

__device__ __forceinline__ unsigned short f32_to_bf16(float f) {
    uint32_t u = __float_as_uint(f);
    uint32_t r = (u + 0x7fffu + ((u >> 16) & 1u)) >> 16;
    return (unsigned short)r;
}

__device__ __forceinline__ void gload_lds16(const void* g, void* l) {
    __builtin_amdgcn_global_load_lds(
        (const __attribute__((address_space(1))) unsigned int*)g,
        (__attribute__((address_space(3))) unsigned int*)l, 16, 0, 0);
}

// ---------------- Phase 0: row-normalize (f64 norm) + bf16 convert ----------------
__global__ void prep_normalize(const float* __restrict__ src, int n_valid,
                               unsigned short* __restrict__ dst,
                               double* __restrict__ inv_out) {
    const int row = blockIdx.x;
    const int t = threadIdx.x;
    __shared__ double s_part[4];
    __shared__ double s_inv;
    unsigned short* drow = dst + (size_t)row * DIM;
    if (row < n_valid) {
        const float4* srow = (const float4*)(src + (size_t)row * DIM);
        float4 v = srow[t];
        double acc = (double)v.x * v.x + (double)v.y * v.y +
                     (double)v.z * v.z + (double)v.w * v.w;
        #pragma unroll
        for (int off = 32; off > 0; off >>= 1) acc += __shfl_down(acc, off);
        if ((t & 63) == 0) s_part[t >> 6] = acc;
        __syncthreads();
        if (t == 0) {
            double nn = sqrt(s_part[0] + s_part[1] + s_part[2] + s_part[3]);
            if (nn < 1e-12) nn = 1e-12;
            double iv = 1.0 / nn;
            s_inv = iv;
            inv_out[row] = iv;
        }
        __syncthreads();
        float iv = (float)s_inv;
        ushort4 o;
        o.x = f32_to_bf16(v.x * iv);
        o.y = f32_to_bf16(v.y * iv);
        o.z = f32_to_bf16(v.z * iv);
        o.w = f32_to_bf16(v.w * iv);
        ((ushort4*)drow)[t] = o;
    } else {
        ushort4 z; z.x = z.y = z.z = z.w = 0;
        ((ushort4*)drow)[t] = z;
        if (t == 0) inv_out[row] = 0.0;
    }
}

// ---------------- Phase A: bf16 MFMA GEMM (BK=64, swizzled LDS, XCD-chunked) ----------
__launch_bounds__(256, 2)
__global__ void approx_topk_gemm(const unsigned short* __restrict__ Abf,  // [1024][1024]
                                 const unsigned short* __restrict__ Bbf,  // [N_PAD][1024]
                                 int* __restrict__ cand_cnt,
                                 int* __restrict__ cand_idx,
                                 float* __restrict__ cand_val) {
    // LDS: [128 rows][64 K] bf16 = 128B rows, seg-swizzled (seg ^= row&7)
    __shared__ unsigned short At[128 * 64];
    __shared__ unsigned short Bt[128 * 64];
    const int t    = threadIdx.x;
    const int lane = t & 63;
    const int w    = t >> 6;
    const int wr   = w >> 1, wc = w & 1;
    const int r16  = lane & 15, kq = lane >> 4;

    // XCD-aware bijective chunked swizzle: 6256 = 8 * 782 exactly
    const int d   = blockIdx.x;
    const int lid = (d & 7) * 782 + (d >> 3);
    const int by  = lid >> 3;             // 0..781 : B column tile
    const int bx  = lid & 7;              // 0..7   : A row tile
    const int brow0 = bx * 128;
    const int bcol0 = by * 128;

    f32x4 acc[4][4];
    #pragma unroll
    for (int m = 0; m < 4; ++m)
        #pragma unroll
        for (int n = 0; n < 4; ++n)
            acc[m][n] = (f32x4){0.f, 0.f, 0.f, 0.f};

    const int srow8 = t >> 3;   // 0..31 (row within a 32-row staging round)
    const int phys  = t & 7;    // physical 16B segment within a 128B row

    for (int kt = 0; kt < DIM / 64; ++kt) {
        #pragma unroll
        for (int R = 0; R < 4; ++R) {
            const int row = R * 32 + srow8;
            const int s   = phys ^ (row & 7);      // logical seg for this phys slot
            gload_lds16(Abf + (size_t)(brow0 + row) * DIM + kt * 64 + s * 8,
                        &At[row * 64 + phys * 8]);
            gload_lds16(Bbf + (size_t)(bcol0 + row) * DIM + kt * 64 + s * 8,
                        &Bt[row * 64 + phys * 8]);
        }
        __syncthreads();
        #pragma unroll
        for (int kh = 0; kh < 2; ++kh) {
            bf16x8 af[4], bfr[4];
            #pragma unroll
            for (int m = 0; m < 4; ++m) {
                const int row = wr * 64 + m * 16 + r16;
                const int ps  = ((kh << 2) | kq) ^ (row & 7);
                af[m] = *(const bf16x8*)&At[row * 64 + ps * 8];
            }
            #pragma unroll
            for (int n = 0; n < 4; ++n) {
                const int row = wc * 64 + n * 16 + r16;
                const int ps  = ((kh << 2) | kq) ^ (row & 7);
                bfr[n] = *(const bf16x8*)&Bt[row * 64 + ps * 8];
            }
            #pragma unroll
            for (int m = 0; m < 4; ++m)
                #pragma unroll
                for (int n = 0; n < 4; ++n)
                    acc[m][n] = __builtin_amdgcn_mfma_f32_16x16x32_bf16(af[m], bfr[n], acc[m][n], 0, 0, 0);
        }
        __syncthreads();
    }

    // epilogue: C/D mapping col = lane&15, row = (lane>>4)*4 + reg
    #pragma unroll
    for (int m = 0; m < 4; ++m) {
        #pragma unroll
        for (int n = 0; n < 4; ++n) {
            const int c = bcol0 + wc * 64 + n * 16 + r16;
            #pragma unroll
            for (int reg = 0; reg < 4; ++reg) {
                float v = acc[m][n][reg];
                if (v >= T_CAND && c < N_DB) {
                    int r = brow0 + wr * 64 + m * 16 + kq * 4 + reg;
                    int pos = atomicAdd(&cand_cnt[r], 1);
                    if (pos < CAND_MAX) {
                        cand_idx[r * CAND_MAX + pos] = c;
                        cand_val[r * CAND_MAX + pos] = v;
                    }
                }
            }
        }
    }
}

// ---------------- Phase B: filter by approx-kth, then exact f64 sims ----------------
__launch_bounds__(256)
__global__ void refine_kernel(const float* __restrict__ query,
                              const float* __restrict__ en_db,
                              const double* __restrict__ q_inv,
                              const double* __restrict__ db_inv,
                              const int* __restrict__ cand_cnt,
                              const int* __restrict__ cand_idx,
                              const float* __restrict__ cand_val,
                              int* __restrict__ surv_cnt,
                              int* __restrict__ surv_idx,
                              double* __restrict__ surv_sim) {
    __shared__ float sv[CAND_MAX];
    __shared__ int   si[CAND_MAX];
    __shared__ int   sL;
    const int b = blockIdx.x;
    const int t = threadIdx.x;
    const int cnt = min(cand_cnt[b], CAND_MAX);
    for (int i = t; i < CAND_MAX; i += 256) {
        if (i < cnt) {
            sv[i] = cand_val[b * CAND_MAX + i];
            si[i] = cand_idx[b * CAND_MAX + i];
        } else {
            sv[i] = -1e30f;
            si[i] = 0x7fffffff;
        }
    }
    if (t == 0) sL = 0;
    __syncthreads();
    // bitonic sort desc by approx val (idx asc tiebreak)
    for (int k = 2; k <= CAND_MAX; k <<= 1) {
        for (int j = k >> 1; j > 0; j >>= 1) {
            for (int i = t; i < CAND_MAX; i += 256) {
                int l = i ^ j;
                if (l > i) {
                    float a = sv[i], c = sv[l];
                    int ia = si[i], ic = si[l];
                    bool iAfter = (a < c) || (a == c && ia > ic);
                    bool lAfter = (c < a) || (c == a && ic > ia);
                    bool dosw = (((i & k) == 0) ? iAfter : lAfter);
                    if (dosw) {
                        sv[i] = c; sv[l] = a;
                        si[i] = ic; si[l] = ia;
                    }
                }
            }
            __syncthreads();
        }
    }
    const float thr = sv[TOPK - 1] - FILT_MARGIN;
    // survivors are a prefix of the sorted array
    {
        int c = 0;
        for (int i = t; i < CAND_MAX; i += 256)
            if (sv[i] >= thr) ++c;
        if (c) atomicAdd(&sL, c);
    }
    __syncthreads();
    const int L = min(sL, SURV_MAX);
    if (t == 0) surv_cnt[b] = L;

    // exact f64 sims for survivors: one wave per candidate, 4 waves
    const int lane = t & 63;
    const int wid  = t >> 6;
    const float4* qg = (const float4*)(query + (size_t)b * DIM);
    float4 qr[4];
    #pragma unroll
    for (int j = 0; j < 4; ++j) qr[j] = qg[j * 64 + lane];
    const double qi = q_inv[b];
    for (int c = wid; c < L; c += 4) {
        const int idx = si[c];
        const float4* dv = (const float4*)(en_db + (size_t)idx * DIM);
        double acc = 0.0;
        #pragma unroll
        for (int j = 0; j < 4; ++j) {
            float4 x = dv[j * 64 + lane];
            float4 q = qr[j];
            acc += (double)x.x * q.x + (double)x.y * q.y +
                   (double)x.z * q.z + (double)x.w * q.w;
        }
        #pragma unroll
        for (int off = 32; off > 0; off >>= 1) acc += __shfl_down(acc, off);
        if (lane == 0) {
            surv_sim[b * SURV_MAX + c] = acc * qi * db_inv[idx];
            surv_idx[b * SURV_MAX + c] = idx;
        }
    }
}

// ---------------- Phase C: sort survivors, top-70, gumbel softmax, gather ----------------
__launch_bounds__(256)
__global__ void finalize_kernel(const float* __restrict__ noise,
                                const float* __restrict__ es_db,
                                const int* __restrict__ surv_cnt,
                                const int* __restrict__ surv_idx,
                                const double* __restrict__ surv_sim,
                                float* __restrict__ out) {
    __shared__ double s_sim[SURV_MAX];
    __shared__ int    s_idx[SURV_MAX];
    __shared__ double s_logit[TOPK];
    __shared__ float  s_w[TOPK];
    __shared__ int    s_top[TOPK];
    const int b = blockIdx.x;
    const int t = threadIdx.x;
    const int cnt = min(surv_cnt[b], SURV_MAX);
    if (t < SURV_MAX) {
        if (t < cnt) {
            s_sim[t] = surv_sim[b * SURV_MAX + t];
            s_idx[t] = surv_idx[b * SURV_MAX + t];
        } else {
            s_sim[t] = -1e300;
            s_idx[t] = 0x7fffffff;
        }
    }
    __syncthreads();
    // bitonic sort 256: sim desc, tie -> idx asc (lax.top_k semantics)
    for (int k = 2; k <= SURV_MAX; k <<= 1) {
        for (int j = k >> 1; j > 0; j >>= 1) {
            if (t < SURV_MAX) {
                int i = t;
                int l = i ^ j;
                if (l > i) {
                    double a = s_sim[i], c = s_sim[l];
                    int ia = s_idx[i], ic = s_idx[l];
                    bool iAfter = (a < c) || (a == c && ia > ic);
                    bool lAfter = (c < a) || (c == a && ic > ia);
                    bool dosw = (((i & k) == 0) ? iAfter : lAfter);
                    if (dosw) {
                        s_sim[i] = c; s_sim[l] = a;
                        s_idx[i] = ic; s_idx[l] = ia;
                    }
                }
            }
            __syncthreads();
        }
    }
    if (t < TOPK) {
        double sim = s_sim[t];
        double u = (double)noise[b * TOPK + t];
        double g = -log(-log(u + 1e-10) + 1e-10);
        s_logit[t] = (sim + g) / 0.1;
        s_top[t] = s_idx[t];
    }
    __syncthreads();
    if (t == 0) {
        double mx = -1e300;
        for (int k = 0; k < TOPK; ++k) mx = fmax(mx, s_logit[k]);
        double sum = 0.0;
        for (int k = 0; k < TOPK; ++k) {
            double ev = exp(s_logit[k] - mx);
            s_logit[k] = ev;
            sum += ev;
        }
        double isum = 1.0 / sum;
        for (int k = 0; k < TOPK; ++k) s_w[k] = (float)(s_logit[k] * isum);
    }
    __syncthreads();
    float4 accv = {0.f, 0.f, 0.f, 0.f};
    for (int k = 0; k < TOPK; ++k) {
        int idx = s_top[k];
        if (idx < N_DB) {
            float4 v = ((const float4*)(es_db + (size_t)idx * DIM))[t];
            float wk = s_w[k];
            accv.x += wk * v.x;
            accv.y += wk * v.y;
            accv.z += wk * v.z;
            accv.w += wk * v.w;
        }
    }
    ((float4*)(out + (size_t)b * DIM))[t] = accv;
}

extern "C" void kernel_launch(void* const* d_in, const int* in_sizes, int n_in,
                              void* d_out, int out_size, void* d_ws, size_t ws_size,
                              hipStream_t stream) {
    const float* query = (const float*)d_in[0];
    const float* en_db = (const float*)d_in[1];
    const float* es_db = (const float*)d_in[2];
    const float* noise = (const float*)d_in[3];
    float* out = (float*)d_out;

    char* ws = (char*)d_ws;
    size_t off = 0;
    unsigned short* db_bf = (unsigned short*)(ws + off); off += (size_t)N_PAD * DIM * 2;
    double* db_inv        = (double*)(ws + off);         off += (size_t)N_PAD * 8;
    unsigned short* q_bf  = (unsigned short*)(ws + off); off += (size_t)B_ROWS * DIM * 2;
    double* q_inv         = (double*)(ws + off);         off += (size_t)B_ROWS * 8;
    int* cand_cnt         = (int*)(ws + off);            off += (size_t)B_ROWS * 4;
    int* cand_idx         = (int*)(ws + off);            off += (size_t)B_ROWS * CAND_MAX * 4;
    float* cand_val       = (float*)(ws + off);          off += (size_t)B_ROWS * CAND_MAX * 4;
    int* surv_cnt         = (int*)(ws + off);            off += (size_t)B_ROWS * 4;
    int* surv_idx         = (int*)(ws + off);            off += (size_t)B_ROWS * SURV_MAX * 4;
    double* surv_sim      = (double*)(ws + off);         off += (size_t)B_ROWS * SURV_MAX * 8;

    hipMemsetAsync(cand_cnt, 0, (size_t)B_ROWS * 4, stream);

    prep_normalize<<<N_PAD, 256, 0, stream>>>(en_db, N_DB, db_bf, db_inv);
    prep_normalize<<<B_ROWS, 256, 0, stream>>>(query, B_ROWS, q_bf, q_inv);

    approx_topk_gemm<<<8 * 782, 256, 0, stream>>>(q_bf, db_bf, cand_cnt, cand_idx, cand_val);

    refine_kernel<<<B_ROWS, 256, 0, stream>>>(query, en_db, q_inv, db_inv,
                                              cand_cnt, cand_idx, cand_val,
                                              surv_cnt, surv_idx, surv_sim);

    finalize_kernel<<<B_ROWS, 256, 0, stream>>>(noise, es_db, surv_cnt, surv_idx,
                                                surv_sim, out);
}